// Round 4
// baseline (129.618 us; speedup 1.0000x reference)
//
#include <hip/hip_runtime.h>

#define NC 5
#define NB 2
#define SPATIAL (128*128*128)
#define NVEC (SPATIAL/4)
#define SMOOTHF 1e-5f
#define NREP 32            // accumulator replicas (31 floats each, padded to 32)
#define GRIDX 2048         // 2048 x 2 blocks x 256 thr -> exactly 1 float4/thread
#define TOTAL_BLOCKS (GRIDX * NB)

// ws layout: float [0 .. NREP*32)  replicated accumulators
//            int   [NREP*32]       target-is-int64 flag
//            int   [NREP*32 + 1]   done-block counter

__global__ __launch_bounds__(1024) void init_and_detect(
    const unsigned long long* __restrict__ t, float* __restrict__ acc) {
    acc[threadIdx.x] = 0.f;                 // zero all NREP*32 replica slots
    if (threadIdx.x == 0) {
        int is64 = 1;
        for (int i = 0; i < 64; ++i)
            if (t[i] >= 5ull) { is64 = 0; break; }
        ((int*)acc)[NREP * 32] = is64;      // P(false pos | int32 data) ~ (1/5)^64
        ((int*)acc)[NREP * 32 + 1] = 0;     // done counter (reset every launch)
    }
}

// No min-waves arg: R2 showed __launch_bounds__(256,8) => pathological spill
// (VGPR forced to 32, 160 MB scratch). R3 showed a 2x unroll => 68 VGPR,
// just over the 64-VGPR occupancy cliff. Single-shot structure keeps the
// live set ~55 VGPR naturally.
__global__ __launch_bounds__(256) void dpdc_main(
    const float* __restrict__ net, const void* __restrict__ targ,
    const float* __restrict__ dist, float* __restrict__ acc,
    float* __restrict__ out)
{
    const int b = blockIdx.y;
    const int t64 = ((const int*)acc)[NREP * 32];
    const float4* nb = (const float4*)(net + (size_t)b * NC * SPATIAL);
    const float4* db = (const float4*)(dist + (size_t)b * SPATIAL);
    const int4* t32p = (const int4*)((const int*)targ + (size_t)b * SPATIAL);
    const ulonglong2* t64p =
        (const ulonglong2*)((const unsigned long long*)targ + (size_t)b * SPATIAL);

    float tp[NC], sp[NC], cnt[NC];
    #pragma unroll
    for (int c = 0; c < NC; ++c) { tp[c] = 0.f; sp[c] = 0.f; cnt[c] = 0.f; }
    float nll = 0.f;

    const int i = blockIdx.x * 256 + threadIdx.x;   // exactly covers NVEC
    {
        float4 l[NC];
        #pragma unroll
        for (int c = 0; c < NC; ++c) l[c] = nb[(size_t)c * NVEC + i];
        float4 dd = db[i];
        int tt[4];
        if (t64) {
            ulonglong2 a = t64p[2 * i];
            ulonglong2 bq = t64p[2 * i + 1];
            tt[0] = (int)a.x; tt[1] = (int)a.y;
            tt[2] = (int)bq.x; tt[3] = (int)bq.y;
        } else {
            int4 a = t32p[i];
            tt[0] = a.x; tt[1] = a.y; tt[2] = a.z; tt[3] = a.w;
        }
        const float* dv = (const float*)&dd;
        #pragma unroll
        for (int j = 0; j < 4; ++j) {
            float lc[NC];
            #pragma unroll
            for (int c = 0; c < NC; ++c) lc[c] = ((const float*)&l[c])[j];
            float m = fmaxf(fmaxf(fmaxf(lc[0], lc[1]), fmaxf(lc[2], lc[3])), lc[4]);
            float e[NC];
            float s = 0.f;
            #pragma unroll
            for (int c = 0; c < NC; ++c) { e[c] = __expf(lc[c] - m); s += e[c]; }
            float inv = 1.0f / s;
            int t = tt[j];
            float lsel = lc[4];
            #pragma unroll
            for (int c = 0; c < 4; ++c) lsel = (t == c) ? lc[c] : lsel;
            float pd = dv[j] * inv;  // dist / sumexp
            #pragma unroll
            for (int c = 0; c < NC; ++c) {
                float p = e[c] * inv;
                sp[c] += p;
                tp[c] += (t == c) ? e[c] * pd : 0.f;
                cnt[c] += (t == c) ? 1.f : 0.f;
            }
            nll += __logf(s) - (lsel - m);
        }
    }

    // block reduction of 16 scalars: tp[5], sp[5], cnt[5], nll
    __shared__ float red[4][16];
    float vals[16];
    #pragma unroll
    for (int c = 0; c < NC; ++c) {
        vals[c] = tp[c]; vals[5 + c] = sp[c]; vals[10 + c] = cnt[c];
    }
    vals[15] = nll;
    const int lane = threadIdx.x & 63;
    const int wave = threadIdx.x >> 6;
    #pragma unroll
    for (int k = 0; k < 16; ++k) {
        float v = vals[k];
        #pragma unroll
        for (int off = 32; off > 0; off >>= 1) v += __shfl_down(v, off, 64);
        if (lane == 0) red[wave][k] = v;
    }
    __syncthreads();
    if (threadIdx.x < 16) {
        int k = threadIdx.x;
        float v = red[0][k] + red[1][k] + red[2][k] + red[3][k];
        float* racc = acc + (blockIdx.x & (NREP - 1)) * 32;
        float* dst;
        if (k < 5)       dst = &racc[b * NC + k];
        else if (k < 10) dst = &racc[10 + b * NC + (k - 5)];
        else if (k < 15) dst = &racc[20 + b * NC + (k - 10)];
        else             dst = &racc[30];
        atomicAdd(dst, v);
    }

    // ---- fused finalize: last block to finish computes the scalar ----
    __shared__ int is_last;
    __syncthreads();                // atomics drained (vmcnt(0)) before barrier
    if (threadIdx.x == 0) {
        __threadfence();
        int* done = (int*)acc + NREP * 32 + 1;
        int old = atomicAdd(done, 1);
        is_last = (old == TOTAL_BLOCKS - 1) ? 1 : 0;
    }
    __syncthreads();
    if (is_last) {
        __shared__ float tot[31];
        if (threadIdx.x == 0) __threadfence();
        __syncthreads();
        if (threadIdx.x < 31) {
            float s = 0.f;
            for (int r = 0; r < NREP; ++r)
                s += __hip_atomic_load(&acc[r * 32 + threadIdx.x],
                                       __ATOMIC_RELAXED,
                                       __HIP_MEMORY_SCOPE_AGENT);
            tot[threadIdx.x] = s;
        }
        __syncthreads();
        if (threadIdx.x == 0) {
            float dcsum = 0.f;
            for (int bb = 0; bb < NB; ++bb)
                for (int c = 0; c < NC; ++c) {
                    float tpv = tot[bb * NC + c];
                    float spv = tot[10 + bb * NC + c];
                    float cv  = tot[20 + bb * NC + c];
                    dcsum += (2.f * tpv + SMOOTHF) / (spv + cv + SMOOTHF);
                }
            float ce = tot[30] / (float)((size_t)NB * SPATIAL);
            out[0] = ce - dcsum / (float)(NB * NC);
        }
    }
}

extern "C" void kernel_launch(void* const* d_in, const int* in_sizes, int n_in,
                              void* d_out, int out_size, void* d_ws, size_t ws_size,
                              hipStream_t stream) {
    const float* net  = (const float*)d_in[0];
    const void*  targ = d_in[1];
    const float* dist = (const float*)d_in[2];
    float* acc = (float*)d_ws;

    init_and_detect<<<1, 1024, 0, stream>>>(
        (const unsigned long long*)targ, acc);
    dim3 grid(GRIDX, NB);
    dpdc_main<<<grid, 256, 0, stream>>>(net, targ, dist, acc, (float*)d_out);
}

// Round 5
// 37.096 us; speedup vs baseline: 3.4942x; 3.4942x over previous
//
#include <hip/hip_runtime.h>

#define NC 5
#define NB 2
#define SPATIAL (128*128*128)
#define NVEC (SPATIAL/4)
#define SMOOTHF 1e-5f
#define NREP 32           // accumulator replicas (31 floats each, padded to 32)
#define GRIDX 1024        // grid (1024, 2) x 256 thr -> exactly 2 float4/thread
#define ITERS (NVEC / (GRIDX * 256))

// ws float layout: [0 .. NREP*32)   replicated accumulators
//                  [NREP*32]        int flag: target-is-int64

__global__ __launch_bounds__(1024) void init_and_detect(
    const unsigned long long* __restrict__ t, float* __restrict__ acc) {
    acc[threadIdx.x] = 0.f;                 // zero all 1024 replica slots
    if (threadIdx.x == 0) {
        int is64 = 1;
        for (int i = 0; i < 64; ++i)
            if (t[i] >= 5ull) { is64 = 0; break; }
        ((int*)acc)[NREP * 32] = is64;      // P(false pos | int32 data) ~ (1/5)^64
    }
}

// Register discipline (hard-won):
//  R2: __launch_bounds__(256,8) -> forced VGPR 32 -> 160 MB scratch spill. Never.
//  R3: #pragma unroll on 2 iters -> 68 VGPR -> over the 64-VGPR cliff -> 4 w/SIMD.
//  R4: device-scope threadfence + done-counter per block -> 6x serialization. Never.
// Here: rolled loop (unroll 1) keeps live set ~44-56 VGPR -> 8 waves/SIMD.
__global__ __launch_bounds__(256) void dpdc_main(
    const float* __restrict__ net, const void* __restrict__ targ,
    const float* __restrict__ dist, float* __restrict__ acc)
{
    const int b = blockIdx.y;
    const int t64 = ((const int*)acc)[NREP * 32];
    const float4* nb = (const float4*)(net + (size_t)b * NC * SPATIAL);
    const float4* db = (const float4*)(dist + (size_t)b * SPATIAL);
    const int4* t32p = (const int4*)((const int*)targ + (size_t)b * SPATIAL);
    const ulonglong2* t64p =
        (const ulonglong2*)((const unsigned long long*)targ + (size_t)b * SPATIAL);

    float tp[NC], sp[NC], cnt[NC];
    #pragma unroll
    for (int c = 0; c < NC; ++c) { tp[c] = 0.f; sp[c] = 0.f; cnt[c] = 0.f; }
    float nll = 0.f;

    int i = blockIdx.x * 256 + threadIdx.x;
    const int stride = GRIDX * 256;
    #pragma unroll 1
    for (int it = 0; it < ITERS; ++it, i += stride) {
        float4 l[NC];
        #pragma unroll
        for (int c = 0; c < NC; ++c) l[c] = nb[(size_t)c * NVEC + i];
        float4 dd = db[i];
        int tt[4];
        if (t64) {
            ulonglong2 a = t64p[2 * i];
            ulonglong2 bq = t64p[2 * i + 1];
            tt[0] = (int)a.x; tt[1] = (int)a.y;
            tt[2] = (int)bq.x; tt[3] = (int)bq.y;
        } else {
            int4 a = t32p[i];
            tt[0] = a.x; tt[1] = a.y; tt[2] = a.z; tt[3] = a.w;
        }
        const float* dv = (const float*)&dd;
        #pragma unroll
        for (int j = 0; j < 4; ++j) {
            float lc[NC];
            #pragma unroll
            for (int c = 0; c < NC; ++c) lc[c] = ((const float*)&l[c])[j];
            float m = fmaxf(fmaxf(fmaxf(lc[0], lc[1]), fmaxf(lc[2], lc[3])), lc[4]);
            float e[NC];
            float s = 0.f;
            #pragma unroll
            for (int c = 0; c < NC; ++c) { e[c] = __expf(lc[c] - m); s += e[c]; }
            float inv = 1.0f / s;
            int t = tt[j];
            float lsel = lc[4];
            #pragma unroll
            for (int c = 0; c < 4; ++c) lsel = (t == c) ? lc[c] : lsel;
            float pd = dv[j] * inv;  // dist / sumexp
            #pragma unroll
            for (int c = 0; c < NC; ++c) {
                float p = e[c] * inv;
                sp[c] += p;
                tp[c] += (t == c) ? e[c] * pd : 0.f;
                cnt[c] += (t == c) ? 1.f : 0.f;
            }
            nll += __logf(s) - (lsel - m);
        }
    }

    // block reduction of 16 scalars: tp[5], sp[5], cnt[5], nll
    __shared__ float red[4][16];
    float vals[16];
    #pragma unroll
    for (int c = 0; c < NC; ++c) {
        vals[c] = tp[c]; vals[5 + c] = sp[c]; vals[10 + c] = cnt[c];
    }
    vals[15] = nll;
    const int lane = threadIdx.x & 63;
    const int wave = threadIdx.x >> 6;
    #pragma unroll
    for (int k = 0; k < 16; ++k) {
        float v = vals[k];
        #pragma unroll
        for (int off = 32; off > 0; off >>= 1) v += __shfl_down(v, off, 64);
        if (lane == 0) red[wave][k] = v;
    }
    __syncthreads();
    if (threadIdx.x < 16) {
        int k = threadIdx.x;
        float v = red[0][k] + red[1][k] + red[2][k] + red[3][k];
        float* racc = acc + (blockIdx.x & (NREP - 1)) * 32;
        float* dst;
        if (k < 5)       dst = &racc[b * NC + k];
        else if (k < 10) dst = &racc[10 + b * NC + (k - 5)];
        else if (k < 15) dst = &racc[20 + b * NC + (k - 10)];
        else             dst = &racc[30];
        atomicAdd(dst, v);
    }
}

__global__ __launch_bounds__(64) void finalize(const float* __restrict__ acc,
                                               float* __restrict__ out) {
    __shared__ float red[31];
    int j = threadIdx.x;
    if (j < 31) {
        float s = 0.f;
        for (int r = 0; r < NREP; ++r) s += acc[r * 32 + j];
        red[j] = s;
    }
    __syncthreads();
    if (j == 0) {
        float dcsum = 0.f;
        for (int b = 0; b < NB; ++b)
            for (int c = 0; c < NC; ++c) {
                float tpv = red[b * NC + c];
                float spv = red[10 + b * NC + c];
                float cv  = red[20 + b * NC + c];
                dcsum += (2.f * tpv + SMOOTHF) / (spv + cv + SMOOTHF);
            }
        float ce = red[30] / (float)((size_t)NB * SPATIAL);
        out[0] = ce - dcsum / (float)(NB * NC);
    }
}

extern "C" void kernel_launch(void* const* d_in, const int* in_sizes, int n_in,
                              void* d_out, int out_size, void* d_ws, size_t ws_size,
                              hipStream_t stream) {
    const float* net  = (const float*)d_in[0];
    const void*  targ = d_in[1];
    const float* dist = (const float*)d_in[2];
    float* acc = (float*)d_ws;

    init_and_detect<<<1, 1024, 0, stream>>>(
        (const unsigned long long*)targ, acc);
    dim3 grid(GRIDX, NB);
    dpdc_main<<<grid, 256, 0, stream>>>(net, targ, dist, acc);
    finalize<<<1, 64, 0, stream>>>(acc, (float*)d_out);
}